// Round 11
// baseline (1325.799 us; speedup 1.0000x reference)
//
#include <hip/hip_runtime.h>
#include <hip/hip_bf16.h>
#include <math.h>

#define B_ 128
#define T_ 256
#define F_ 64
#define H_ 512
#define G4_ 2048

// LDS layout (bytes)
#define XB0_OFF 0            // 32KB x tile (even t)
#define XB1_OFF 32768        // 32KB x tile (odd t)
#define HB_OFF  65536        // 32KB h tile
#define GLDX_OFF 98304       // [8][32][17] f32 x-part gates = 17408B
#define GLDH_OFF 115712      // [8][32][17] f32 h-part gates = 17408B
#define SMEM_TOTAL 133120

typedef __attribute__((ext_vector_type(8))) short bf16x8;
typedef __attribute__((ext_vector_type(4))) float f32x4;

__device__ __forceinline__ void coh_store_u32(unsigned* p, unsigned v) {
  __hip_atomic_store(p, v, __ATOMIC_RELAXED, __HIP_MEMORY_SCOPE_AGENT);
}
__device__ __forceinline__ unsigned coh_load_u32(const unsigned* p) {
  return __hip_atomic_load(p, __ATOMIC_RELAXED, __HIP_MEMORY_SCOPE_AGENT);
}
__device__ __forceinline__ void rawbar() { __builtin_amdgcn_s_barrier(); }

// async 16B/lane global->LDS; LDS dest = uniform base + lane*16 (HW rule)
// aux=0: plain cached (static data); aux=17: SC0|SC1 device-coherent (fresh)
__device__ __forceinline__ void async_ld16(const void* g, void* l) {
  __builtin_amdgcn_global_load_lds(
      (const __attribute__((address_space(1))) void*)g,
      (__attribute__((address_space(3))) void*)l, 16, 0, 0);
}
__device__ __forceinline__ void async_ld16c(const void* g, void* l) {
  __builtin_amdgcn_global_load_lds(
      (const __attribute__((address_space(1))) void*)g,
      (__attribute__((address_space(3))) void*)l, 16, 0, 17);
}

__device__ __forceinline__ float fsig(float x) {
  float e = __builtin_amdgcn_exp2f(-1.44269504089f * x);
  return __builtin_amdgcn_rcpf(1.f + e);
}
__device__ __forceinline__ float ftanh(float x) {
  float ax = __builtin_fabsf(x);
  float e = __builtin_amdgcn_exp2f(-2.88539008177f * ax);
  float r = (1.f - e) * __builtin_amdgcn_rcpf(1.f + e);
  return __builtin_copysignf(r, x);
}

// ---- transpose+cast four [512,2048] fp32 weight mats -> [2048,512] bf16 ----
__global__ __launch_bounds__(256) void transpose_cast_k(
    const float* __restrict__ s0, const float* __restrict__ s1,
    const float* __restrict__ s2, const float* __restrict__ s3,
    __hip_bfloat16* __restrict__ dst)
{
  __shared__ float lds[64][65];
  const float* src = (blockIdx.z == 0) ? s0 : (blockIdx.z == 1) ? s1 : (blockIdx.z == 2) ? s2 : s3;
  __hip_bfloat16* d = dst + (size_t)blockIdx.z * (G4_ * H_);
  int n0 = blockIdx.x * 64, k0 = blockIdx.y * 64;
  int tx = threadIdx.x & 63, ty = threadIdx.x >> 6;
#pragma unroll
  for (int r = 0; r < 16; r++) { int k = r * 4 + ty; lds[k][tx] = src[(size_t)(k0 + k) * G4_ + n0 + tx]; }
  __syncthreads();
#pragma unroll
  for (int r = 0; r < 16; r++) { int n = r * 4 + ty; d[(size_t)(n0 + n) * H_ + k0 + tx] = __float2bfloat16(lds[tx][n]); }
}

// ---- cast W1 to bf16 + zero state buffers & sync counters ----
__global__ void prep_misc_k(const float* __restrict__ w1, __hip_bfloat16* __restrict__ w1b,
                            float* __restrict__ zbase, int nzero)
{
  int i = blockIdx.x * blockDim.x + threadIdx.x;
  int stride = gridDim.x * blockDim.x;
  for (int k = i; k < F_ * H_; k += stride) w1b[k] = __float2bfloat16(w1[k]);
  for (int k = i; k < nzero; k += stride) zbase[k] = 0.f;
}

// ---- dense1 + spectral-norm row normalization; h0 out as bf16 [B*T, H] ----
__global__ __launch_bounds__(512) void dense1_k(
    const float* __restrict__ x, const __hip_bfloat16* __restrict__ w1b,
    const float* __restrict__ b1, __hip_bfloat16* __restrict__ h0)
{
  __shared__ float red[8];
  int j = threadIdx.x;
  int wave = j >> 6, lane = j & 63;
  float wcol[64];
#pragma unroll
  for (int k = 0; k < 64; k++) wcol[k] = __bfloat162float(w1b[k * H_ + j]);
  float bj = b1[j];
  for (int r = 0; r < 32; r++) {
    int row = blockIdx.x * 32 + r;
    const float* xr = x + (size_t)row * F_;
    float acc = bj;
#pragma unroll
    for (int k = 0; k < 64; k++) acc += xr[k] * wcol[k];
    float ss = acc * acc;
#pragma unroll
    for (int o = 32; o; o >>= 1) ss += __shfl_down(ss, o);
    if (lane == 0) red[wave] = ss;
    __syncthreads();
    float tot = red[0] + red[1] + red[2] + red[3] + red[4] + red[5] + red[6] + red[7];
    float sc = sqrtf(512.f) / fmaxf(sqrtf(tot), 1e-12f);
    h0[(size_t)row * H_ + j] = __float2bfloat16(acc * sc);
    __syncthreads();
  }
}

// one K-split MFMA chain: 8 kc chunks of A from LDS, weights from regs,
// two independent accumulators; one A-read feeds TWO MFMAs (key ratio)
#define RUN_CHAIN(BASEPTR, W0, W1, A0, A1)                                    \
  {                                                                           \
    const char* _cb = (const char*)(BASEPTR);                                 \
    _Pragma("unroll")                                                         \
    for (int kc = 0; kc < 8; kc++) {                                          \
      bf16x8 _av = *(const bf16x8*)(_cb + ((mh * 16 + kh * 8 + kc) << 10) + (lane << 4)); \
      A0 = __builtin_amdgcn_mfma_f32_16x16x32_bf16(_av, W0[kc], A0, 0, 0, 0); \
      A1 = __builtin_amdgcn_mfma_f32_16x16x32_bf16(_av, W1[kc], A1, 0, 0, 0); \
    }                                                                         \
  }

// ---- fused persistent LSTM1+LSTM2 ----
// Round 22 = round-17 base (928us, best) + three additive cuts, tail kept
// EXACTLY (round-21's top-moved x-prefetch regressed: the post-publish
// window already hid the x drain; pre-D contention delayed h instead):
//  1. NO D barrier: each wave issues ALL 8 h chunks it consumes (pair
//     partners issue duplicates -- concurrent identical-byte LDS DMA is
//     benign), so h-readiness is a per-wave vmcnt(0), not a barrier join.
//  2. x-part gates (ready since last step) written to gldx at the TOP,
//     during the h flight; only the h-gate write (gldh) stays on the
//     critical path. elem sums gldx+gldh.
//  3. hot-spin first 48 polls before s_sleep (detect dequantized).
// 2 barriers/step: exchange bar (post-lgkm) and B2. AGENT coherence only.
__global__ __launch_bounds__(512, 2) void lstm_fused_k(
    const __hip_bfloat16* __restrict__ h0,     // [B*T, H] dense1 out (LSTM1 x)
    __hip_bfloat16* __restrict__ seq,          // [B*T, H] LSTM1 out / LSTM2 x
    const __hip_bfloat16* __restrict__ wh1, const __hip_bfloat16* __restrict__ wx1,
    const float* __restrict__ bl1,
    const __hip_bfloat16* __restrict__ wh2, const __hip_bfloat16* __restrict__ wx2,
    const float* __restrict__ bl2,
    __hip_bfloat16* __restrict__ h1A, __hip_bfloat16* __restrict__ h1B,
    __hip_bfloat16* __restrict__ h2A, __hip_bfloat16* __restrict__ h2B,
    float* __restrict__ h2f,                   // [B, H] fp32 final h of LSTM2
    unsigned* flags)                           // 8 counters, 1KB stride
{
  extern __shared__ char smem[];
  float* gldx = (float*)(smem + GLDX_OFF);
  float* gldh = (float*)(smem + GLDH_OFF);
  const int tid = threadIdx.x;
  const int wave = tid >> 6;
  const int lane = tid & 63;
  const int lr = lane & 15;
  const int lk = lane >> 4;
  const int bid = blockIdx.x;
  const int grp = bid >> 7;       // 0 = LSTM1 producer, 1 = LSTM2 consumer
  const int lid = bid & 127;
  const int bb = lid & 3;         // batch strip (32 rows) == sync domain
  const int bu = lid >> 2;        // unit strip (16 cols), 0..31
  const int m0 = bb * 32;
  const int u0 = bu * 16;

  const int kh = wave >> 2;        // K half (0:k<256, 1:k>=256)
  const int mh = (wave >> 1) & 1;  // row half (0:m<16, 1:m>=16)
  const int gp = wave & 1;         // gate pair (gates 2gp, 2gp+1)

  const __hip_bfloat16* Wht = grp ? wh2 : wh1;
  const __hip_bfloat16* Wxt = grp ? wx2 : wx1;
  const __hip_bfloat16* xsrc = grp ? (const __hip_bfloat16*)seq : h0;
  const float* bias = grp ? bl2 : bl1;
  __hip_bfloat16* hgA = grp ? h2A : h1A;   // grp0: unused (h comes from seq)
  __hip_bfloat16* hgB = grp ? h2B : h1B;
  unsigned* cown  = flags + (((grp << 2) | bb) << 8);   // own-group counter
  unsigned* cprod = flags + (bb << 8);                  // grp0 counter

  // ---- weights -> registers: per wave 2 gate-col-tiles x K-half, Wh+Wx ----
  bf16x8 wh_0[8], wh_1[8], wx_0[8], wx_1[8];
  {
    const size_t c0 = (size_t)((gp * 2 + 0) * 512 + u0 + lr) * H_ + kh * 256 + lk * 8;
    const size_t c1 = (size_t)((gp * 2 + 1) * 512 + u0 + lr) * H_ + kh * 256 + lk * 8;
#pragma unroll
    for (int kc = 0; kc < 8; kc++) {
      wh_0[kc] = *(const bf16x8*)(Wht + c0 + kc * 32);
      wh_1[kc] = *(const bf16x8*)(Wht + c1 + kc * 32);
      wx_0[kc] = *(const bf16x8*)(Wxt + c0 + kc * 32);
      wx_1[kc] = *(const bf16x8*)(Wxt + c1 + kc * 32);
    }
#pragma unroll
    for (int kc = 0; kc < 8; kc++) {
      asm volatile("" : "+v"(wh_0[kc]), "+v"(wh_1[kc]), "+v"(wx_0[kc]), "+v"(wx_1[kc]));
    }
  }

  const int m_e = tid >> 3, up_e = tid & 7;
  float br0[2], br1[2], br2[2], br3[2];
  float2 creg = {0.f, 0.f};
  if (tid < 256) {
#pragma unroll
    for (int c = 0; c < 2; c++) {
      br0[c] = bias[0 * 512 + u0 + 2 * up_e + c];
      br1[c] = bias[1 * 512 + u0 + 2 * up_e + c];
      br2[c] = bias[2 * 512 + u0 + 2 * up_e + c];
      br3[c] = bias[3 * 512 + u0 + 2 * up_e + c];
    }
  }

  char* xb0 = smem + XB0_OFF;
  char* xb1 = smem + XB1_OFF;

  auto issue_x = [&](int t, char* xb) {   // stage x[t] tile (32 rows x 512)
#pragma unroll
    for (int j = 0; j < 4; j++) {
      const int c = wave * 4 + j;
      const __hip_bfloat16* g = xsrc +
          ((size_t)(m0 + (c >> 4) * 16 + lr) * T_ + t) * H_ + (c & 15) * 32 + lk * 8;
      if (grp) async_ld16c(g, xb + c * 1024);   // seq: device-coherent
      else     async_ld16(g, xb + c * 1024);    // h0: static, stays cached
    }
  };
  // stage h(u-1): wave issues the full 8-chunk span it CONSUMES (pair
  // partners issue identical duplicates -> per-wave vmcnt readiness)
  auto issue_h_span = [&](int u) {
    const int s = mh * 16 + kh * 8;
#pragma unroll
    for (int j = 0; j < 8; j++) {
      const int c = s + j;
      const int row = m0 + (c >> 4) * 16 + lr;
      const __hip_bfloat16* g;
      if (grp) {
        const __hip_bfloat16* hsrc = ((u - 1) & 1) ? hgB : hgA;
        g = hsrc + (size_t)row * H_ + (c & 15) * 32 + lk * 8;
      } else {
        g = seq + ((size_t)row * T_ + (u - 1)) * H_ + (c & 15) * 32 + lk * 8;
      }
      async_ld16c(g, smem + HB_OFF + c * 1024);
    }
  };
  // wave-uniform counter wait (same-address broadcast); hot-spin then sleep
  auto wait2 = [&](unsigned t0, bool need1, unsigned t1) {
    int n = 0;
    while (true) {
      unsigned v0 = coh_load_u32(cown);
      if (v0 >= t0) {
        if (!need1) break;
        unsigned v1 = coh_load_u32(cprod);
        if (v1 >= t1) break;
      }
      if (++n > 48) __builtin_amdgcn_s_sleep(2);
    }
  };
  auto spinA = [&](int u) {
    const bool need1 = (grp == 1) && (u <= T_ - 3);
    wait2((unsigned)(32 * u), need1, (unsigned)(32 * (u + 3)));
  };
  auto publish = [&]() {
    if (tid == 0) atomicAdd(cown, 1u);
  };
  auto write_gld = [&](float* g, f32x4 s0, f32x4 s1) {
    float* d0 = g + ((kh * 4 + gp * 2 + 0) * 32 + mh * 16 + lk * 4) * 17 + lr;
    float* d1 = g + ((kh * 4 + gp * 2 + 1) * 32 + mh * 16 + lk * 4) * 17 + lr;
#pragma unroll
    for (int r = 0; r < 4; r++) { d0[r * 17] = s0[r]; d1[r * 17] = s1[r]; }
  };
  auto elem = [&](int u, __hip_bfloat16* hout, bool with_h) {
    if (tid < 256) {
      float gv0[2], gv1[2], gv2[2], gv3[2];
#pragma unroll
      for (int c = 0; c < 2; c++) {
        const int o = m_e * 17 + 2 * up_e + c;
        gv0[c] = gldx[(0 * 32) * 17 + o] + gldx[(4 * 32) * 17 + o] + br0[c];
        gv1[c] = gldx[(1 * 32) * 17 + o] + gldx[(5 * 32) * 17 + o] + br1[c];
        gv2[c] = gldx[(2 * 32) * 17 + o] + gldx[(6 * 32) * 17 + o] + br2[c];
        gv3[c] = gldx[(3 * 32) * 17 + o] + gldx[(7 * 32) * 17 + o] + br3[c];
        if (with_h) {
          gv0[c] += gldh[(0 * 32) * 17 + o] + gldh[(4 * 32) * 17 + o];
          gv1[c] += gldh[(1 * 32) * 17 + o] + gldh[(5 * 32) * 17 + o];
          gv2[c] += gldh[(2 * 32) * 17 + o] + gldh[(6 * 32) * 17 + o];
          gv3[c] += gldh[(3 * 32) * 17 + o] + gldh[(7 * 32) * 17 + o];
        }
      }
      float i0 = fsig(gv0[0]), i1 = fsig(gv0[1]);
      float f0 = fsig(gv1[0]), f1 = fsig(gv1[1]);
      float cb0 = ftanh(gv2[0]), cb1 = ftanh(gv2[1]);
      float o0 = fsig(gv3[0]), o1 = fsig(gv3[1]);
      float cn0 = f0 * creg.x + i0 * cb0;
      float cn1 = f1 * creg.y + i1 * cb1;
      creg.x = cn0; creg.y = cn1;
      float hv0 = o0 * ftanh(cn0), hv1 = o1 * ftanh(cn1);
      union { __hip_bfloat16 h[2]; unsigned u32; } pk;
      pk.h[0] = __float2bfloat16(hv0);
      pk.h[1] = __float2bfloat16(hv1);
      const int row = m0 + m_e, col = u0 + 2 * up_e;
      if (grp == 0) {
        // h(u) lives only in seq -- peers re-load it from there next step
        coh_store_u32((unsigned*)seq + (((size_t)row * T_ + u) * H_ + col) / 2, pk.u32);
      } else {
        coh_store_u32((unsigned*)hout + ((size_t)row * H_ + col) / 2, pk.u32);
        if (u == T_ - 1) {
          float2 hv = {hv0, hv1};
          *(float2*)(h2f + (size_t)row * H_ + col) = hv;  // kernel-end flush
        }
      }
    }
  };

  f32x4 axc0 = {0.f,0.f,0.f,0.f}, axc1 = {0.f,0.f,0.f,0.f};
  f32x4 axn0, axn1, ah0, ah1;

  // -------- prologue: step 0 (h=0, x-part only) --------
  if (grp) wait2(0u, true, 96u);             // grp0 finished steps 0..2
  issue_x(0, xb0);
  issue_x(1, xb1);
  asm volatile("s_waitcnt vmcnt(0)" ::: "memory");
  rawbar();
  __builtin_amdgcn_sched_barrier(0);
  RUN_CHAIN(xb0, wx_0, wx_1, axc0, axc1);    // x-part of step 0
  write_gld(gldx, axc0, axc1);
  asm volatile("s_waitcnt lgkmcnt(0)" ::: "memory");
  rawbar();
  __builtin_amdgcn_sched_barrier(0);
  elem(0, hgA, false);
  issue_x(2, xb0);                           // stores older than these loads
  asm volatile("s_waitcnt vmcnt(4)" ::: "memory");   // stores drained
  publish();                                 // h(0) visible
  asm volatile("s_waitcnt vmcnt(0)" ::: "memory");   // x(2) landed
  rawbar();
  __builtin_amdgcn_sched_barrier(0);
  axc0 = (f32x4){0.f,0.f,0.f,0.f}; axc1 = (f32x4){0.f,0.f,0.f,0.f};
  RUN_CHAIN(xb1, wx_0, wx_1, axc0, axc1);    // x-part of step 1

  // -------- main loop: u = 1..255 --------
  for (int u = 1; u < T_; u++) {
    __hip_bfloat16* hout = (u & 1) ? hgB : hgA;
    const bool pf = (u <= T_ - 3);

    // A. spin: peers' h(u) ready (+ grp1 lag guard for x(u+2))
    spinA(u);
    // B. issue own h span (8 chunks); park x-gates in gldx (off crit path)
    issue_h_span(u);
    write_gld(gldx, axc0, axc1);
    // C. x-GEMM(u+1) covers part of the h flight
    if (u < T_ - 1) {
      axn0 = (f32x4){0.f,0.f,0.f,0.f}; axn1 = (f32x4){0.f,0.f,0.f,0.f};
      char* xb = ((u + 1) & 1) ? xb1 : xb0;
      RUN_CHAIN(xb, wx_0, wx_1, axn0, axn1);
    }
    // D'. own h span landed -- per-wave wait, NO barrier
    asm volatile("s_waitcnt vmcnt(0)" ::: "memory");
    // E. h-GEMM(u) + h-gate staging; single exchange barrier
    ah0 = (f32x4){0.f,0.f,0.f,0.f}; ah1 = (f32x4){0.f,0.f,0.f,0.f};
    RUN_CHAIN(smem + HB_OFF, wh_0, wh_1, ah0, ah1);
    write_gld(gldh, ah0, ah1);
    asm volatile("s_waitcnt lgkmcnt(0)" ::: "memory");
    rawbar();
    __builtin_amdgcn_sched_barrier(0);
    // F. elementwise + single h/seq store
    elem(u, hout, true);
    // G. tail (round-17 proven): prefetch, drain stores, publish, drain x
    if (pf) {
      issue_x(u + 2, (u & 1) ? xb1 : xb0);
      asm volatile("s_waitcnt vmcnt(4)" ::: "memory");
      publish();
      asm volatile("s_waitcnt vmcnt(0)" ::: "memory");
    } else {
      asm volatile("s_waitcnt vmcnt(0)" ::: "memory");
      publish();
    }
    rawbar();   // B2: xb(u+2) + HB + gld protected
    __builtin_amdgcn_sched_barrier(0);
    axc0 = axn0; axc1 = axn1;
  }
}

// ---- LayerNorm + dense2(relu) + dense3; one block per batch row ----
__global__ __launch_bounds__(256) void final_k(
    const float* __restrict__ h2, const float* __restrict__ gamma, const float* __restrict__ beta,
    const float* __restrict__ W2, const float* __restrict__ b2,
    const float* __restrict__ W3, const float* __restrict__ b3, float* __restrict__ out)
{
  __shared__ float y[512];
  __shared__ float redS[4], redQ[4], redP[4];
  int b = blockIdx.x, tid = threadIdx.x;
  int wave = tid >> 6, lane = tid & 63;
  float v0 = h2[b * H_ + tid], v1 = h2[b * H_ + 256 + tid];
  float s = v0 + v1, q = v0 * v0 + v1 * v1;
#pragma unroll
  for (int o = 32; o; o >>= 1) { s += __shfl_down(s, o); q += __shfl_down(q, o); }
  if (lane == 0) { redS[wave] = s; redQ[wave] = q; }
  __syncthreads();
  float tot = redS[0] + redS[1] + redS[2] + redS[3];
  float totq = redQ[0] + redQ[1] + redQ[2] + redQ[3];
  float mu = tot * (1.f / 512.f);
  float var = totq * (1.f / 512.f) - mu * mu;
  float rs = rsqrtf(var + 1e-3f);
  y[tid]       = (v0 - mu) * rs * gamma[tid] + beta[tid];
  y[tid + 256] = (v1 - mu) * rs * gamma[tid + 256] + beta[tid + 256];
  __syncthreads();
  float acc = b2[tid];
  for (int k = 0; k < 512; k++) acc += y[k] * W2[k * 256 + tid];
  float pv = fmaxf(acc, 0.f) * W3[tid];
#pragma unroll
  for (int o = 32; o; o >>= 1) pv += __shfl_down(pv, o);
  if (lane == 0) redP[wave] = pv;
  __syncthreads();
  if (tid == 0) out[b] = redP[0] + redP[1] + redP[2] + redP[3] + b3[0];
}

extern "C" void kernel_launch(void* const* d_in, const int* in_sizes, int n_in,
                              void* d_out, int out_size, void* d_ws, size_t ws_size,
                              hipStream_t stream)
{
  (void)in_sizes; (void)n_in; (void)out_size; (void)ws_size;
  const float* x    = (const float*)d_in[0];
  const float* W1   = (const float*)d_in[1];
  const float* b1   = (const float*)d_in[2];
  const float* Wx1  = (const float*)d_in[3];
  const float* Wh1  = (const float*)d_in[4];
  const float* bl1  = (const float*)d_in[5];
  const float* Wx2  = (const float*)d_in[6];
  const float* Wh2  = (const float*)d_in[7];
  const float* bl2  = (const float*)d_in[8];
  const float* gam  = (const float*)d_in[9];
  const float* bet  = (const float*)d_in[10];
  const float* W2   = (const float*)d_in[11];
  const float* b2   = (const float*)d_in[12];
  const float* W3   = (const float*)d_in[13];
  const float* b3   = (const float*)d_in[14];

  char* p = (char*)d_ws;
  const size_t MB = 1024 * 1024;
  __hip_bfloat16* wx1t = (__hip_bfloat16*)(p + 0 * MB);
  __hip_bfloat16* wh1t = (__hip_bfloat16*)(p + 2 * MB);
  __hip_bfloat16* wx2t = (__hip_bfloat16*)(p + 4 * MB);
  __hip_bfloat16* wh2t = (__hip_bfloat16*)(p + 6 * MB);
  __hip_bfloat16* w1b  = (__hip_bfloat16*)(p + 8 * MB);
  __hip_bfloat16* h0   = (__hip_bfloat16*)(p + 9 * MB);   // 32 MB
  __hip_bfloat16* seq  = (__hip_bfloat16*)(p + 41 * MB);  // 32 MB
  char* st = p + 73 * MB;
  __hip_bfloat16* h1A = (__hip_bfloat16*)st;                       // 4x128KB
  __hip_bfloat16* h1B = h1A + B_ * H_;
  __hip_bfloat16* h2A = h1B + B_ * H_;
  __hip_bfloat16* h2B = h2A + B_ * H_;
  float* h2f = (float*)(st + 512 * 1024);                          // 256KB
  unsigned* flags = (unsigned*)(st + 512 * 1024 + 256 * 1024);     // 8KB counters
  int nzero = (int)((512 * 1024 + 256 * 1024 + 16384) / 4);

  transpose_cast_k<<<dim3(32, 8, 4), 256, 0, stream>>>(Wx1, Wh1, Wx2, Wh2, wx1t);
  prep_misc_k<<<256, 256, 0, stream>>>(W1, w1b, (float*)st, nzero);
  dense1_k<<<1024, 512, 0, stream>>>(x, w1b, b1, h0);

  void* args[] = { (void*)&h0, (void*)&seq,
                   (void*)&wh1t, (void*)&wx1t, (void*)&bl1,
                   (void*)&wh2t, (void*)&wx2t, (void*)&bl2,
                   (void*)&h1A, (void*)&h1B, (void*)&h2A, (void*)&h2B,
                   (void*)&h2f, (void*)&flags };
  hipLaunchCooperativeKernel((void*)lstm_fused_k, dim3(256), dim3(512), args,
                             SMEM_TOTAL, stream);

  final_k<<<128, 256, 0, stream>>>(h2f, gam, bet, W2, b2, W3, b3, (float*)d_out);
}

// Round 12
// 1144.256 us; speedup vs baseline: 1.1587x; 1.1587x over previous
//
#include <hip/hip_runtime.h>
#include <hip/hip_bf16.h>
#include <math.h>

#define B_ 128
#define T_ 256
#define F_ 64
#define H_ 512
#define G4_ 2048

// LDS layout (bytes)
#define XB0_OFF 0            // 32KB x tile (even t)
#define XB1_OFF 32768        // 32KB x tile (odd t)
#define HB_OFF  65536        // 32KB h tile
#define GLD_OFF 98304        // [8][32][17] f32 partial gates = 17408B
#define SMEM_TOTAL 115712

typedef __attribute__((ext_vector_type(8))) short bf16x8;
typedef __attribute__((ext_vector_type(4))) float f32x4;

__device__ __forceinline__ void coh_store_u32(unsigned* p, unsigned v) {
  __hip_atomic_store(p, v, __ATOMIC_RELAXED, __HIP_MEMORY_SCOPE_AGENT);
}
__device__ __forceinline__ unsigned coh_load_u32(const unsigned* p) {
  return __hip_atomic_load(p, __ATOMIC_RELAXED, __HIP_MEMORY_SCOPE_AGENT);
}
__device__ __forceinline__ void rawbar() { __builtin_amdgcn_s_barrier(); }

// async 16B/lane global->LDS; LDS dest = uniform base + lane*16 (HW rule)
// aux=0: plain cached (static data); aux=17: SC0|SC1 device-coherent (fresh)
__device__ __forceinline__ void async_ld16(const void* g, void* l) {
  __builtin_amdgcn_global_load_lds(
      (const __attribute__((address_space(1))) void*)g,
      (__attribute__((address_space(3))) void*)l, 16, 0, 0);
}
__device__ __forceinline__ void async_ld16c(const void* g, void* l) {
  __builtin_amdgcn_global_load_lds(
      (const __attribute__((address_space(1))) void*)g,
      (__attribute__((address_space(3))) void*)l, 16, 0, 17);
}

__device__ __forceinline__ float fsig(float x) {
  float e = __builtin_amdgcn_exp2f(-1.44269504089f * x);
  return __builtin_amdgcn_rcpf(1.f + e);
}
__device__ __forceinline__ float ftanh(float x) {
  float ax = __builtin_fabsf(x);
  float e = __builtin_amdgcn_exp2f(-2.88539008177f * ax);
  float r = (1.f - e) * __builtin_amdgcn_rcpf(1.f + e);
  return __builtin_copysignf(r, x);
}

// ---- transpose+cast four [512,2048] fp32 weight mats -> [2048,512] bf16 ----
__global__ __launch_bounds__(256) void transpose_cast_k(
    const float* __restrict__ s0, const float* __restrict__ s1,
    const float* __restrict__ s2, const float* __restrict__ s3,
    __hip_bfloat16* __restrict__ dst)
{
  __shared__ float lds[64][65];
  const float* src = (blockIdx.z == 0) ? s0 : (blockIdx.z == 1) ? s1 : (blockIdx.z == 2) ? s2 : s3;
  __hip_bfloat16* d = dst + (size_t)blockIdx.z * (G4_ * H_);
  int n0 = blockIdx.x * 64, k0 = blockIdx.y * 64;
  int tx = threadIdx.x & 63, ty = threadIdx.x >> 6;
#pragma unroll
  for (int r = 0; r < 16; r++) { int k = r * 4 + ty; lds[k][tx] = src[(size_t)(k0 + k) * G4_ + n0 + tx]; }
  __syncthreads();
#pragma unroll
  for (int r = 0; r < 16; r++) { int n = r * 4 + ty; d[(size_t)(n0 + n) * H_ + k0 + tx] = __float2bfloat16(lds[tx][n]); }
}

// ---- cast W1 to bf16 + zero state buffers & sync counters ----
__global__ void prep_misc_k(const float* __restrict__ w1, __hip_bfloat16* __restrict__ w1b,
                            float* __restrict__ zbase, int nzero)
{
  int i = blockIdx.x * blockDim.x + threadIdx.x;
  int stride = gridDim.x * blockDim.x;
  for (int k = i; k < F_ * H_; k += stride) w1b[k] = __float2bfloat16(w1[k]);
  for (int k = i; k < nzero; k += stride) zbase[k] = 0.f;
}

// ---- dense1 + spectral-norm row normalization; h0 out as bf16 [B*T, H] ----
__global__ __launch_bounds__(512) void dense1_k(
    const float* __restrict__ x, const __hip_bfloat16* __restrict__ w1b,
    const float* __restrict__ b1, __hip_bfloat16* __restrict__ h0)
{
  __shared__ float red[8];
  int j = threadIdx.x;
  int wave = j >> 6, lane = j & 63;
  float wcol[64];
#pragma unroll
  for (int k = 0; k < 64; k++) wcol[k] = __bfloat162float(w1b[k * H_ + j]);
  float bj = b1[j];
  for (int r = 0; r < 32; r++) {
    int row = blockIdx.x * 32 + r;
    const float* xr = x + (size_t)row * F_;
    float acc = bj;
#pragma unroll
    for (int k = 0; k < 64; k++) acc += xr[k] * wcol[k];
    float ss = acc * acc;
#pragma unroll
    for (int o = 32; o; o >>= 1) ss += __shfl_down(ss, o);
    if (lane == 0) red[wave] = ss;
    __syncthreads();
    float tot = red[0] + red[1] + red[2] + red[3] + red[4] + red[5] + red[6] + red[7];
    float sc = sqrtf(512.f) / fmaxf(sqrtf(tot), 1e-12f);
    h0[(size_t)row * H_ + j] = __float2bfloat16(acc * sc);
    __syncthreads();
  }
}

// one K-split MFMA chain: 8 kc chunks of A from LDS, weights from regs,
// two independent accumulators; one A-read feeds TWO MFMAs (key ratio)
#define RUN_CHAIN(BASEPTR, W0, W1, A0, A1)                                    \
  {                                                                           \
    const char* _cb = (const char*)(BASEPTR);                                 \
    _Pragma("unroll")                                                         \
    for (int kc = 0; kc < 8; kc++) {                                          \
      bf16x8 _av = *(const bf16x8*)(_cb + ((mh * 16 + kh * 8 + kc) << 10) + (lane << 4)); \
      A0 = __builtin_amdgcn_mfma_f32_16x16x32_bf16(_av, W0[kc], A0, 0, 0, 0); \
      A1 = __builtin_amdgcn_mfma_f32_16x16x32_bf16(_av, W1[kc], A1, 0, 0, 0); \
    }                                                                         \
  }

// ---- fused persistent LSTM1+LSTM2 ----
// Round 23 = round-17 base (928us lstm, best measured; r21/r22 reorderings
// both regressed -- the r17 tail already hides its drains behind the peers'
// detect window) + ONE change: single-wave sync duty. Only wave 7 polls the
// counters and stages the h tile (all 32 chunks); waves 0-6 go straight to
// the x-GEMM and join at the D barrier. Cuts the same-address L3 poll storm
// 8x (2048 -> 256 polling waves chip-wide) and overlaps detect with 7/8 of
// the block's x-GEMM. Everything else byte-identical to round-17.
__global__ __launch_bounds__(512, 2) void lstm_fused_k(
    const __hip_bfloat16* __restrict__ h0,     // [B*T, H] dense1 out (LSTM1 x)
    __hip_bfloat16* __restrict__ seq,          // [B*T, H] LSTM1 out / LSTM2 x
    const __hip_bfloat16* __restrict__ wh1, const __hip_bfloat16* __restrict__ wx1,
    const float* __restrict__ bl1,
    const __hip_bfloat16* __restrict__ wh2, const __hip_bfloat16* __restrict__ wx2,
    const float* __restrict__ bl2,
    __hip_bfloat16* __restrict__ h1A, __hip_bfloat16* __restrict__ h1B,
    __hip_bfloat16* __restrict__ h2A, __hip_bfloat16* __restrict__ h2B,
    float* __restrict__ h2f,                   // [B, H] fp32 final h of LSTM2
    unsigned* flags)                           // 8 counters, 1KB stride
{
  extern __shared__ char smem[];
  float* gld = (float*)(smem + GLD_OFF);
  const int tid = threadIdx.x;
  const int wave = tid >> 6;
  const int lane = tid & 63;
  const int lr = lane & 15;
  const int lk = lane >> 4;
  const int bid = blockIdx.x;
  const int grp = bid >> 7;       // 0 = LSTM1 producer, 1 = LSTM2 consumer
  const int lid = bid & 127;
  const int bb = lid & 3;         // batch strip (32 rows) == sync domain
  const int bu = lid >> 2;        // unit strip (16 cols), 0..31
  const int m0 = bb * 32;
  const int u0 = bu * 16;

  const int kh = wave >> 2;        // K half (0:k<256, 1:k>=256)
  const int mh = (wave >> 1) & 1;  // row half (0:m<16, 1:m>=16)
  const int gp = wave & 1;         // gate pair (gates 2gp, 2gp+1)

  const __hip_bfloat16* Wht = grp ? wh2 : wh1;
  const __hip_bfloat16* Wxt = grp ? wx2 : wx1;
  const __hip_bfloat16* xsrc = grp ? (const __hip_bfloat16*)seq : h0;
  const float* bias = grp ? bl2 : bl1;
  __hip_bfloat16* hgA = grp ? h2A : h1A;   // grp0: unused (h comes from seq)
  __hip_bfloat16* hgB = grp ? h2B : h1B;
  unsigned* cown  = flags + (((grp << 2) | bb) << 8);   // own-group counter
  unsigned* cprod = flags + (bb << 8);                  // grp0 counter

  // ---- weights -> registers: per wave 2 gate-col-tiles x K-half, Wh+Wx ----
  bf16x8 wh_0[8], wh_1[8], wx_0[8], wx_1[8];
  {
    const size_t c0 = (size_t)((gp * 2 + 0) * 512 + u0 + lr) * H_ + kh * 256 + lk * 8;
    const size_t c1 = (size_t)((gp * 2 + 1) * 512 + u0 + lr) * H_ + kh * 256 + lk * 8;
#pragma unroll
    for (int kc = 0; kc < 8; kc++) {
      wh_0[kc] = *(const bf16x8*)(Wht + c0 + kc * 32);
      wh_1[kc] = *(const bf16x8*)(Wht + c1 + kc * 32);
      wx_0[kc] = *(const bf16x8*)(Wxt + c0 + kc * 32);
      wx_1[kc] = *(const bf16x8*)(Wxt + c1 + kc * 32);
    }
#pragma unroll
    for (int kc = 0; kc < 8; kc++) {
      asm volatile("" : "+v"(wh_0[kc]), "+v"(wh_1[kc]), "+v"(wx_0[kc]), "+v"(wx_1[kc]));
    }
  }

  const int m_e = tid >> 3, up_e = tid & 7;
  float br0[2], br1[2], br2[2], br3[2];
  float2 creg = {0.f, 0.f};
  if (tid < 256) {
#pragma unroll
    for (int c = 0; c < 2; c++) {
      br0[c] = bias[0 * 512 + u0 + 2 * up_e + c];
      br1[c] = bias[1 * 512 + u0 + 2 * up_e + c];
      br2[c] = bias[2 * 512 + u0 + 2 * up_e + c];
      br3[c] = bias[3 * 512 + u0 + 2 * up_e + c];
    }
  }

  char* xb0 = smem + XB0_OFF;
  char* xb1 = smem + XB1_OFF;

  auto issue_x = [&](int t, char* xb) {   // stage x[t] tile (32 rows x 512)
#pragma unroll
    for (int j = 0; j < 4; j++) {
      const int c = wave * 4 + j;
      const __hip_bfloat16* g = xsrc +
          ((size_t)(m0 + (c >> 4) * 16 + lr) * T_ + t) * H_ + (c & 15) * 32 + lk * 8;
      if (grp) async_ld16c(g, xb + c * 1024);   // seq: device-coherent
      else     async_ld16(g, xb + c * 1024);    // h0: static, stays cached
    }
  };
  // stage h(u-1), ALL 32 chunks -- called by wave 7 only in the main loop
  auto issue_h_all = [&](int u) {
#pragma unroll
    for (int c = 0; c < 32; c++) {
      const int row = m0 + (c >> 4) * 16 + lr;
      const __hip_bfloat16* g;
      if (grp) {
        const __hip_bfloat16* hsrc = ((u - 1) & 1) ? hgB : hgA;
        g = hsrc + (size_t)row * H_ + (c & 15) * 32 + lk * 8;
      } else {
        g = seq + ((size_t)row * T_ + (u - 1)) * H_ + (c & 15) * 32 + lk * 8;
      }
      async_ld16c(g, smem + HB_OFF + c * 1024);
    }
  };
  // wave-uniform counter wait: same-address load (HW broadcast)
  auto wait2 = [&](unsigned t0, bool need1, unsigned t1) {
    while (true) {
      unsigned v0 = coh_load_u32(cown);
      if (v0 >= t0) {
        if (!need1) break;
        unsigned v1 = coh_load_u32(cprod);
        if (v1 >= t1) break;
      }
      __builtin_amdgcn_s_sleep(1);
    }
  };
  auto spinA = [&](int u) {
    const bool need1 = (grp == 1) && (u <= T_ - 3);
    wait2((unsigned)(32 * u), need1, (unsigned)(32 * (u + 3)));
  };
  auto publish = [&]() {
    if (tid == 0) atomicAdd(cown, 1u);
  };
  auto write_gld = [&](f32x4 s0, f32x4 s1) {
    float* d0 = gld + ((kh * 4 + gp * 2 + 0) * 32 + mh * 16 + lk * 4) * 17 + lr;
    float* d1 = gld + ((kh * 4 + gp * 2 + 1) * 32 + mh * 16 + lk * 4) * 17 + lr;
#pragma unroll
    for (int r = 0; r < 4; r++) { d0[r * 17] = s0[r]; d1[r * 17] = s1[r]; }
  };
  auto elem = [&](int u, __hip_bfloat16* hout) {
    if (tid < 256) {
      float gv0[2], gv1[2], gv2[2], gv3[2];
#pragma unroll
      for (int c = 0; c < 2; c++) {
        const int o = m_e * 17 + 2 * up_e + c;
        gv0[c] = gld[(0 * 32) * 17 + o] + gld[(4 * 32) * 17 + o] + br0[c];
        gv1[c] = gld[(1 * 32) * 17 + o] + gld[(5 * 32) * 17 + o] + br1[c];
        gv2[c] = gld[(2 * 32) * 17 + o] + gld[(6 * 32) * 17 + o] + br2[c];
        gv3[c] = gld[(3 * 32) * 17 + o] + gld[(7 * 32) * 17 + o] + br3[c];
      }
      float i0 = fsig(gv0[0]), i1 = fsig(gv0[1]);
      float f0 = fsig(gv1[0]), f1 = fsig(gv1[1]);
      float cb0 = ftanh(gv2[0]), cb1 = ftanh(gv2[1]);
      float o0 = fsig(gv3[0]), o1 = fsig(gv3[1]);
      float cn0 = f0 * creg.x + i0 * cb0;
      float cn1 = f1 * creg.y + i1 * cb1;
      creg.x = cn0; creg.y = cn1;
      float hv0 = o0 * ftanh(cn0), hv1 = o1 * ftanh(cn1);
      union { __hip_bfloat16 h[2]; unsigned u32; } pk;
      pk.h[0] = __float2bfloat16(hv0);
      pk.h[1] = __float2bfloat16(hv1);
      const int row = m0 + m_e, col = u0 + 2 * up_e;
      if (grp == 0) {
        // h(u) lives only in seq -- peers re-load it from there next step
        coh_store_u32((unsigned*)seq + (((size_t)row * T_ + u) * H_ + col) / 2, pk.u32);
      } else {
        coh_store_u32((unsigned*)hout + ((size_t)row * H_ + col) / 2, pk.u32);
        if (u == T_ - 1) {
          float2 hv = {hv0, hv1};
          *(float2*)(h2f + (size_t)row * H_ + col) = hv;  // kernel-end flush
        }
      }
    }
  };

  f32x4 axc0 = {0.f,0.f,0.f,0.f}, axc1 = {0.f,0.f,0.f,0.f};
  f32x4 axn0, axn1, ah0, ah1;

  // -------- prologue: step 0 (h=0, x-part only) --------
  if (grp) wait2(0u, true, 96u);             // grp0 finished steps 0..2
  issue_x(0, xb0);
  issue_x(1, xb1);
  asm volatile("s_waitcnt vmcnt(0)" ::: "memory");
  rawbar();
  __builtin_amdgcn_sched_barrier(0);
  RUN_CHAIN(xb0, wx_0, wx_1, axc0, axc1);    // x-part of step 0
  write_gld(axc0, axc1);
  asm volatile("s_waitcnt lgkmcnt(0)" ::: "memory");
  rawbar();
  __builtin_amdgcn_sched_barrier(0);
  elem(0, hgA);
  issue_x(2, xb0);
  asm volatile("s_waitcnt vmcnt(4)" ::: "memory");   // store drained
  publish();
  asm volatile("s_waitcnt vmcnt(0)" ::: "memory");   // x(2) landed
  rawbar();
  __builtin_amdgcn_sched_barrier(0);
  axc0 = (f32x4){0.f,0.f,0.f,0.f}; axc1 = (f32x4){0.f,0.f,0.f,0.f};
  RUN_CHAIN(xb1, wx_0, wx_1, axc0, axc1);    // x-part of step 1

  // -------- main loop: u = 1..255 --------
  for (int u = 1; u < T_; u++) {
    __hip_bfloat16* hout = (u & 1) ? hgB : hgA;
    const bool pf = (u <= T_ - 3);

    // A/B. single-wave sync duty: w7 spins (peers' h(u) + grp1 lag guard)
    //      and stages the whole h tile; w0-6 go straight to compute.
    if (wave == 7) {
      spinA(u);
      issue_h_all(u);
    }
    // C. x-GEMM(u+1) (xb valid since last iter's B2 barrier)
    if (u < T_ - 1) {
      axn0 = (f32x4){0.f,0.f,0.f,0.f}; axn1 = (f32x4){0.f,0.f,0.f,0.f};
      char* xb = ((u + 1) & 1) ? xb1 : xb0;
      RUN_CHAIN(xb, wx_0, wx_1, axn0, axn1);
    }
    // D. h landed (w7's loads); barrier joins at max(compute, spin+flight)
    if (wave == 7) asm volatile("s_waitcnt vmcnt(0)" ::: "memory");
    rawbar();
    __builtin_amdgcn_sched_barrier(0);
    // E. h-GEMM(u) + gate staging
    ah0 = (f32x4){0.f,0.f,0.f,0.f}; ah1 = (f32x4){0.f,0.f,0.f,0.f};
    RUN_CHAIN(smem + HB_OFF, wh_0, wh_1, ah0, ah1);
    write_gld(axc0 + ah0, axc1 + ah1);
    asm volatile("s_waitcnt lgkmcnt(0)" ::: "memory");
    rawbar();
    __builtin_amdgcn_sched_barrier(0);
    // F. elementwise + single h/seq store; then next-next x prefetch
    elem(u, hout);
    if (pf) {
      issue_x(u + 2, (u & 1) ? xb1 : xb0);
      // stores (older) drained; the 4 newest x-loads stay in flight
      asm volatile("s_waitcnt vmcnt(4)" ::: "memory");
      // publish early -- counter travels while we drain the prefetch
      publish();
      // x(u+2) landed (overlaps peers' detect)
      asm volatile("s_waitcnt vmcnt(0)" ::: "memory");
    } else {
      asm volatile("s_waitcnt vmcnt(0)" ::: "memory");
      publish();
    }
    rawbar();   // B2: xb(u+2) ready block-wide; gld reusable
    axc0 = axn0; axc1 = axn1;
  }
}

// ---- LayerNorm + dense2(relu) + dense3; one block per batch row ----
__global__ __launch_bounds__(256) void final_k(
    const float* __restrict__ h2, const float* __restrict__ gamma, const float* __restrict__ beta,
    const float* __restrict__ W2, const float* __restrict__ b2,
    const float* __restrict__ W3, const float* __restrict__ b3, float* __restrict__ out)
{
  __shared__ float y[512];
  __shared__ float redS[4], redQ[4], redP[4];
  int b = blockIdx.x, tid = threadIdx.x;
  int wave = tid >> 6, lane = tid & 63;
  float v0 = h2[b * H_ + tid], v1 = h2[b * H_ + 256 + tid];
  float s = v0 + v1, q = v0 * v0 + v1 * v1;
#pragma unroll
  for (int o = 32; o; o >>= 1) { s += __shfl_down(s, o); q += __shfl_down(q, o); }
  if (lane == 0) { redS[wave] = s; redQ[wave] = q; }
  __syncthreads();
  float tot = redS[0] + redS[1] + redS[2] + redS[3];
  float totq = redQ[0] + redQ[1] + redQ[2] + redQ[3];
  float mu = tot * (1.f / 512.f);
  float var = totq * (1.f / 512.f) - mu * mu;
  float rs = rsqrtf(var + 1e-3f);
  y[tid]       = (v0 - mu) * rs * gamma[tid] + beta[tid];
  y[tid + 256] = (v1 - mu) * rs * gamma[tid + 256] + beta[tid + 256];
  __syncthreads();
  float acc = b2[tid];
  for (int k = 0; k < 512; k++) acc += y[k] * W2[k * 256 + tid];
  float pv = fmaxf(acc, 0.f) * W3[tid];
#pragma unroll
  for (int o = 32; o; o >>= 1) pv += __shfl_down(pv, o);
  if (lane == 0) redP[wave] = pv;
  __syncthreads();
  if (tid == 0) out[b] = redP[0] + redP[1] + redP[2] + redP[3] + b3[0];
}

extern "C" void kernel_launch(void* const* d_in, const int* in_sizes, int n_in,
                              void* d_out, int out_size, void* d_ws, size_t ws_size,
                              hipStream_t stream)
{
  (void)in_sizes; (void)n_in; (void)out_size; (void)ws_size;
  const float* x    = (const float*)d_in[0];
  const float* W1   = (const float*)d_in[1];
  const float* b1   = (const float*)d_in[2];
  const float* Wx1  = (const float*)d_in[3];
  const float* Wh1  = (const float*)d_in[4];
  const float* bl1  = (const float*)d_in[5];
  const float* Wx2  = (const float*)d_in[6];
  const float* Wh2  = (const float*)d_in[7];
  const float* bl2  = (const float*)d_in[8];
  const float* gam  = (const float*)d_in[9];
  const float* bet  = (const float*)d_in[10];
  const float* W2   = (const float*)d_in[11];
  const float* b2   = (const float*)d_in[12];
  const float* W3   = (const float*)d_in[13];
  const float* b3   = (const float*)d_in[14];

  char* p = (char*)d_ws;
  const size_t MB = 1024 * 1024;
  __hip_bfloat16* wx1t = (__hip_bfloat16*)(p + 0 * MB);
  __hip_bfloat16* wh1t = (__hip_bfloat16*)(p + 2 * MB);
  __hip_bfloat16* wx2t = (__hip_bfloat16*)(p + 4 * MB);
  __hip_bfloat16* wh2t = (__hip_bfloat16*)(p + 6 * MB);
  __hip_bfloat16* w1b  = (__hip_bfloat16*)(p + 8 * MB);
  __hip_bfloat16* h0   = (__hip_bfloat16*)(p + 9 * MB);   // 32 MB
  __hip_bfloat16* seq  = (__hip_bfloat16*)(p + 41 * MB);  // 32 MB
  char* st = p + 73 * MB;
  __hip_bfloat16* h1A = (__hip_bfloat16*)st;                       // 4x128KB
  __hip_bfloat16* h1B = h1A + B_ * H_;
  __hip_bfloat16* h2A = h1B + B_ * H_;
  __hip_bfloat16* h2B = h2A + B_ * H_;
  float* h2f = (float*)(st + 512 * 1024);                          // 256KB
  unsigned* flags = (unsigned*)(st + 512 * 1024 + 256 * 1024);     // 8KB counters
  int nzero = (int)((512 * 1024 + 256 * 1024 + 16384) / 4);

  transpose_cast_k<<<dim3(32, 8, 4), 256, 0, stream>>>(Wx1, Wh1, Wx2, Wh2, wx1t);
  prep_misc_k<<<256, 256, 0, stream>>>(W1, w1b, (float*)st, nzero);
  dense1_k<<<1024, 512, 0, stream>>>(x, w1b, b1, h0);

  void* args[] = { (void*)&h0, (void*)&seq,
                   (void*)&wh1t, (void*)&wx1t, (void*)&bl1,
                   (void*)&wh2t, (void*)&wx2t, (void*)&bl2,
                   (void*)&h1A, (void*)&h1B, (void*)&h2A, (void*)&h2B,
                   (void*)&h2f, (void*)&flags };
  hipLaunchCooperativeKernel((void*)lstm_fused_k, dim3(256), dim3(512), args,
                             SMEM_TOTAL, stream);

  final_k<<<128, 256, 0, stream>>>(h2f, gam, bet, W2, b2, W3, b3, (float*)d_out);
}

// Round 13
// 1122.943 us; speedup vs baseline: 1.1806x; 1.0190x over previous
//
#include <hip/hip_runtime.h>
#include <hip/hip_bf16.h>
#include <math.h>

#define B_ 128
#define T_ 256
#define F_ 64
#define H_ 512
#define G4_ 2048

// LDS layout (bytes)
#define XB0_OFF 0            // 32KB x tile (even t)
#define XB1_OFF 32768        // 32KB x tile (odd t)
#define HB_OFF  65536        // 32KB h tile
#define GLD_OFF 98304        // [8][32][17] f32 partial gates = 17408B
#define SMEM_TOTAL 115712

typedef __attribute__((ext_vector_type(8))) short bf16x8;
typedef __attribute__((ext_vector_type(4))) float f32x4;

__device__ __forceinline__ void coh_store_u32(unsigned* p, unsigned v) {
  __hip_atomic_store(p, v, __ATOMIC_RELAXED, __HIP_MEMORY_SCOPE_AGENT);
}
__device__ __forceinline__ unsigned coh_load_u32(const unsigned* p) {
  return __hip_atomic_load(p, __ATOMIC_RELAXED, __HIP_MEMORY_SCOPE_AGENT);
}
__device__ __forceinline__ void rawbar() { __builtin_amdgcn_s_barrier(); }

// async 16B/lane global->LDS; LDS dest = uniform base + lane*16 (HW rule)
// aux=0: plain cached (static data); aux=17: SC0|SC1 device-coherent (fresh)
__device__ __forceinline__ void async_ld16(const void* g, void* l) {
  __builtin_amdgcn_global_load_lds(
      (const __attribute__((address_space(1))) void*)g,
      (__attribute__((address_space(3))) void*)l, 16, 0, 0);
}
__device__ __forceinline__ void async_ld16c(const void* g, void* l) {
  __builtin_amdgcn_global_load_lds(
      (const __attribute__((address_space(1))) void*)g,
      (__attribute__((address_space(3))) void*)l, 16, 0, 17);
}

__device__ __forceinline__ float fsig(float x) {
  float e = __builtin_amdgcn_exp2f(-1.44269504089f * x);
  return __builtin_amdgcn_rcpf(1.f + e);
}
__device__ __forceinline__ float ftanh(float x) {
  float ax = __builtin_fabsf(x);
  float e = __builtin_amdgcn_exp2f(-2.88539008177f * ax);
  float r = (1.f - e) * __builtin_amdgcn_rcpf(1.f + e);
  return __builtin_copysignf(r, x);
}

// ---- transpose+cast four [512,2048] fp32 weight mats -> [2048,512] bf16 ----
__global__ __launch_bounds__(256) void transpose_cast_k(
    const float* __restrict__ s0, const float* __restrict__ s1,
    const float* __restrict__ s2, const float* __restrict__ s3,
    __hip_bfloat16* __restrict__ dst)
{
  __shared__ float lds[64][65];
  const float* src = (blockIdx.z == 0) ? s0 : (blockIdx.z == 1) ? s1 : (blockIdx.z == 2) ? s2 : s3;
  __hip_bfloat16* d = dst + (size_t)blockIdx.z * (G4_ * H_);
  int n0 = blockIdx.x * 64, k0 = blockIdx.y * 64;
  int tx = threadIdx.x & 63, ty = threadIdx.x >> 6;
#pragma unroll
  for (int r = 0; r < 16; r++) { int k = r * 4 + ty; lds[k][tx] = src[(size_t)(k0 + k) * G4_ + n0 + tx]; }
  __syncthreads();
#pragma unroll
  for (int r = 0; r < 16; r++) { int n = r * 4 + ty; d[(size_t)(n0 + n) * H_ + k0 + tx] = __float2bfloat16(lds[tx][n]); }
}

// ---- cast W1 to bf16 + zero state buffers & sync counters ----
__global__ void prep_misc_k(const float* __restrict__ w1, __hip_bfloat16* __restrict__ w1b,
                            float* __restrict__ zbase, int nzero)
{
  int i = blockIdx.x * blockDim.x + threadIdx.x;
  int stride = gridDim.x * blockDim.x;
  for (int k = i; k < F_ * H_; k += stride) w1b[k] = __float2bfloat16(w1[k]);
  for (int k = i; k < nzero; k += stride) zbase[k] = 0.f;
}

// ---- dense1 + spectral-norm row normalization; h0 out as bf16 [B*T, H] ----
__global__ __launch_bounds__(512) void dense1_k(
    const float* __restrict__ x, const __hip_bfloat16* __restrict__ w1b,
    const float* __restrict__ b1, __hip_bfloat16* __restrict__ h0)
{
  __shared__ float red[8];
  int j = threadIdx.x;
  int wave = j >> 6, lane = j & 63;
  float wcol[64];
#pragma unroll
  for (int k = 0; k < 64; k++) wcol[k] = __bfloat162float(w1b[k * H_ + j]);
  float bj = b1[j];
  for (int r = 0; r < 32; r++) {
    int row = blockIdx.x * 32 + r;
    const float* xr = x + (size_t)row * F_;
    float acc = bj;
#pragma unroll
    for (int k = 0; k < 64; k++) acc += xr[k] * wcol[k];
    float ss = acc * acc;
#pragma unroll
    for (int o = 32; o; o >>= 1) ss += __shfl_down(ss, o);
    if (lane == 0) red[wave] = ss;
    __syncthreads();
    float tot = red[0] + red[1] + red[2] + red[3] + red[4] + red[5] + red[6] + red[7];
    float sc = sqrtf(512.f) / fmaxf(sqrtf(tot), 1e-12f);
    h0[(size_t)row * H_ + j] = __float2bfloat16(acc * sc);
    __syncthreads();
  }
}

// one K-split MFMA chain: 8 kc chunks of A from LDS, weights from regs,
// two independent accumulators (the two gate-column tiles of this wave)
#define RUN_CHAIN(BASEPTR, W0, W1, A0, A1)                                    \
  {                                                                           \
    const char* _cb = (const char*)(BASEPTR);                                 \
    _Pragma("unroll")                                                         \
    for (int kc = 0; kc < 8; kc++) {                                          \
      bf16x8 _av = *(const bf16x8*)(_cb + ((mh * 16 + kh * 8 + kc) << 10) + (lane << 4)); \
      A0 = __builtin_amdgcn_mfma_f32_16x16x32_bf16(_av, W0[kc], A0, 0, 0, 0); \
      A1 = __builtin_amdgcn_mfma_f32_16x16x32_bf16(_av, W1[kc], A1, 0, 0, 0); \
    }                                                                         \
  }

// ---- fused persistent LSTM1+LSTM2 ----
// FINAL (round 24) = round-17 configuration, the session's best measured
// (lstm dispatch 928us, end-to-end 1125us vs 1643us at session start).
// Structure: 8 waves (2/SIMD), K-split MFMA with weights pinned in regs
// (AGPR half of unified file), 3 barriers/step, aggregate-counter sync
// (publish = atomicAdd, detect = wave-uniform same-address load), h-load
// covered by next-step x-GEMM, tail prefetch drain hidden behind peers'
// detect window. Exploration record: sc0 XCD-local sync (r12: watchdog
// storm), gate-interleaved full-K mapping (r15/18/19: 2x A-frag reads +
// redundant elem, ~1330us floor), top-moved x-prefetch (r21), span-dup
// h staging (r22), w7-only sync (r23) -- all neutral or regressions.
// Remaining gap to MFMA peak is the per-step AGENT-scope RT chain
// (publish->detect->coherent h flight), structural at this decomposition.
__global__ __launch_bounds__(512, 2) void lstm_fused_k(
    const __hip_bfloat16* __restrict__ h0,     // [B*T, H] dense1 out (LSTM1 x)
    __hip_bfloat16* __restrict__ seq,          // [B*T, H] LSTM1 out / LSTM2 x
    const __hip_bfloat16* __restrict__ wh1, const __hip_bfloat16* __restrict__ wx1,
    const float* __restrict__ bl1,
    const __hip_bfloat16* __restrict__ wh2, const __hip_bfloat16* __restrict__ wx2,
    const float* __restrict__ bl2,
    __hip_bfloat16* __restrict__ h1A, __hip_bfloat16* __restrict__ h1B,
    __hip_bfloat16* __restrict__ h2A, __hip_bfloat16* __restrict__ h2B,
    float* __restrict__ h2f,                   // [B, H] fp32 final h of LSTM2
    unsigned* flags)                           // 8 counters, 1KB stride
{
  extern __shared__ char smem[];
  float* gld = (float*)(smem + GLD_OFF);
  const int tid = threadIdx.x;
  const int wave = tid >> 6;
  const int lane = tid & 63;
  const int lr = lane & 15;
  const int lk = lane >> 4;
  const int bid = blockIdx.x;
  const int grp = bid >> 7;       // 0 = LSTM1 producer, 1 = LSTM2 consumer
  const int lid = bid & 127;
  const int bb = lid & 3;         // batch strip (32 rows) == sync domain
  const int bu = lid >> 2;        // unit strip (16 cols), 0..31
  const int m0 = bb * 32;
  const int u0 = bu * 16;

  const int kh = wave >> 2;        // K half (0:k<256, 1:k>=256)
  const int mh = (wave >> 1) & 1;  // row half (0:m<16, 1:m>=16)
  const int gp = wave & 1;         // gate pair (gates 2gp, 2gp+1)

  const __hip_bfloat16* Wht = grp ? wh2 : wh1;
  const __hip_bfloat16* Wxt = grp ? wx2 : wx1;
  const __hip_bfloat16* xsrc = grp ? (const __hip_bfloat16*)seq : h0;
  const float* bias = grp ? bl2 : bl1;
  __hip_bfloat16* hgA = grp ? h2A : h1A;   // grp0: unused (h comes from seq)
  __hip_bfloat16* hgB = grp ? h2B : h1B;
  unsigned* cown  = flags + (((grp << 2) | bb) << 8);   // own-group counter
  unsigned* cprod = flags + (bb << 8);                  // grp0 counter

  // ---- weights -> registers: per wave 2 gate-col-tiles x K-half, Wh+Wx ----
  bf16x8 wh_0[8], wh_1[8], wx_0[8], wx_1[8];
  {
    const size_t c0 = (size_t)((gp * 2 + 0) * 512 + u0 + lr) * H_ + kh * 256 + lk * 8;
    const size_t c1 = (size_t)((gp * 2 + 1) * 512 + u0 + lr) * H_ + kh * 256 + lk * 8;
#pragma unroll
    for (int kc = 0; kc < 8; kc++) {
      wh_0[kc] = *(const bf16x8*)(Wht + c0 + kc * 32);
      wh_1[kc] = *(const bf16x8*)(Wht + c1 + kc * 32);
      wx_0[kc] = *(const bf16x8*)(Wxt + c0 + kc * 32);
      wx_1[kc] = *(const bf16x8*)(Wxt + c1 + kc * 32);
    }
#pragma unroll
    for (int kc = 0; kc < 8; kc++) {
      asm volatile("" : "+v"(wh_0[kc]), "+v"(wh_1[kc]), "+v"(wx_0[kc]), "+v"(wx_1[kc]));
    }
  }

  const int m_e = tid >> 3, up_e = tid & 7;
  float br0[2], br1[2], br2[2], br3[2];
  float2 creg = {0.f, 0.f};
  if (tid < 256) {
#pragma unroll
    for (int c = 0; c < 2; c++) {
      br0[c] = bias[0 * 512 + u0 + 2 * up_e + c];
      br1[c] = bias[1 * 512 + u0 + 2 * up_e + c];
      br2[c] = bias[2 * 512 + u0 + 2 * up_e + c];
      br3[c] = bias[3 * 512 + u0 + 2 * up_e + c];
    }
  }

  char* xb0 = smem + XB0_OFF;
  char* xb1 = smem + XB1_OFF;

  auto issue_x = [&](int t, char* xb) {   // stage x[t] tile (32 rows x 512)
#pragma unroll
    for (int j = 0; j < 4; j++) {
      const int c = wave * 4 + j;
      const __hip_bfloat16* g = xsrc +
          ((size_t)(m0 + (c >> 4) * 16 + lr) * T_ + t) * H_ + (c & 15) * 32 + lk * 8;
      if (grp) async_ld16c(g, xb + c * 1024);   // seq: device-coherent
      else     async_ld16(g, xb + c * 1024);    // h0: static, stays cached
    }
  };
  // stage h(u-1): grp0 reads seq column u-1; grp1 reads the double buffer
  auto issue_h = [&](int u) {
#pragma unroll
    for (int j = 0; j < 4; j++) {
      const int c = wave * 4 + j;
      const int row = m0 + (c >> 4) * 16 + lr;
      const __hip_bfloat16* g;
      if (grp) {
        const __hip_bfloat16* hsrc = ((u - 1) & 1) ? hgB : hgA;
        g = hsrc + (size_t)row * H_ + (c & 15) * 32 + lk * 8;
      } else {
        g = seq + ((size_t)row * T_ + (u - 1)) * H_ + (c & 15) * 32 + lk * 8;
      }
      async_ld16c(g, smem + HB_OFF + c * 1024);
    }
  };
  // wave-uniform counter wait: all lanes load the SAME address (HW broadcast
  // -> 1 L3 transaction per wave per poll); branch is uniform.
  auto wait2 = [&](unsigned t0, bool need1, unsigned t1) {
    while (true) {
      unsigned v0 = coh_load_u32(cown);
      if (v0 >= t0) {
        if (!need1) break;
        unsigned v1 = coh_load_u32(cprod);
        if (v1 >= t1) break;
      }
      __builtin_amdgcn_s_sleep(1);
    }
  };
  auto spinA = [&](int u) {
    const bool need1 = (grp == 1) && (u <= T_ - 3);
    wait2((unsigned)(32 * u), need1, (unsigned)(32 * (u + 3)));
  };
  auto publish = [&]() {
    if (tid == 0) atomicAdd(cown, 1u);
  };
  auto write_gld = [&](f32x4 s0, f32x4 s1) {
    float* d0 = gld + ((kh * 4 + gp * 2 + 0) * 32 + mh * 16 + lk * 4) * 17 + lr;
    float* d1 = gld + ((kh * 4 + gp * 2 + 1) * 32 + mh * 16 + lk * 4) * 17 + lr;
#pragma unroll
    for (int r = 0; r < 4; r++) { d0[r * 17] = s0[r]; d1[r * 17] = s1[r]; }
  };
  auto elem = [&](int u, __hip_bfloat16* hout) {
    if (tid < 256) {
      float gv0[2], gv1[2], gv2[2], gv3[2];
#pragma unroll
      for (int c = 0; c < 2; c++) {
        const int o = m_e * 17 + 2 * up_e + c;
        gv0[c] = gld[(0 * 32) * 17 + o] + gld[(4 * 32) * 17 + o] + br0[c];
        gv1[c] = gld[(1 * 32) * 17 + o] + gld[(5 * 32) * 17 + o] + br1[c];
        gv2[c] = gld[(2 * 32) * 17 + o] + gld[(6 * 32) * 17 + o] + br2[c];
        gv3[c] = gld[(3 * 32) * 17 + o] + gld[(7 * 32) * 17 + o] + br3[c];
      }
      float i0 = fsig(gv0[0]), i1 = fsig(gv0[1]);
      float f0 = fsig(gv1[0]), f1 = fsig(gv1[1]);
      float cb0 = ftanh(gv2[0]), cb1 = ftanh(gv2[1]);
      float o0 = fsig(gv3[0]), o1 = fsig(gv3[1]);
      float cn0 = f0 * creg.x + i0 * cb0;
      float cn1 = f1 * creg.y + i1 * cb1;
      creg.x = cn0; creg.y = cn1;
      float hv0 = o0 * ftanh(cn0), hv1 = o1 * ftanh(cn1);
      union { __hip_bfloat16 h[2]; unsigned u32; } pk;
      pk.h[0] = __float2bfloat16(hv0);
      pk.h[1] = __float2bfloat16(hv1);
      const int row = m0 + m_e, col = u0 + 2 * up_e;
      if (grp == 0) {
        // h(u) lives only in seq -- peers re-load it from there next step
        coh_store_u32((unsigned*)seq + (((size_t)row * T_ + u) * H_ + col) / 2, pk.u32);
      } else {
        coh_store_u32((unsigned*)hout + ((size_t)row * H_ + col) / 2, pk.u32);
        if (u == T_ - 1) {
          float2 hv = {hv0, hv1};
          *(float2*)(h2f + (size_t)row * H_ + col) = hv;  // kernel-end flush
        }
      }
    }
  };

  f32x4 axc0 = {0.f,0.f,0.f,0.f}, axc1 = {0.f,0.f,0.f,0.f};
  f32x4 axn0, axn1, ah0, ah1;

  // -------- prologue: step 0 (h=0, x-part only) --------
  if (grp) wait2(0u, true, 96u);             // grp0 finished steps 0..2
  issue_x(0, xb0);
  issue_x(1, xb1);
  asm volatile("s_waitcnt vmcnt(0)" ::: "memory");
  rawbar();
  __builtin_amdgcn_sched_barrier(0);
  RUN_CHAIN(xb0, wx_0, wx_1, axc0, axc1);    // x-part of step 0
  write_gld(axc0, axc1);
  asm volatile("s_waitcnt lgkmcnt(0)" ::: "memory");
  rawbar();
  __builtin_amdgcn_sched_barrier(0);
  elem(0, hgA);
  issue_x(2, xb0);
  asm volatile("s_waitcnt vmcnt(4)" ::: "memory");   // store drained
  publish();
  asm volatile("s_waitcnt vmcnt(0)" ::: "memory");   // x(2) landed
  rawbar();
  __builtin_amdgcn_sched_barrier(0);
  axc0 = (f32x4){0.f,0.f,0.f,0.f}; axc1 = (f32x4){0.f,0.f,0.f,0.f};
  RUN_CHAIN(xb1, wx_0, wx_1, axc0, axc1);    // x-part of step 1

  // -------- main loop: u = 1..255 --------
  for (int u = 1; u < T_; u++) {
    __hip_bfloat16* hout = (u & 1) ? hgB : hgA;
    const bool pf = (u <= T_ - 3);

    // A. spin: peers' h(u) ready (+ grp1 lag guard)
    spinA(u);
    // B. stage fresh h (device-coherent)
    issue_h(u);
    // C. x-GEMM(u+1) covers part of the h flight
    if (u < T_ - 1) {
      axn0 = (f32x4){0.f,0.f,0.f,0.f}; axn1 = (f32x4){0.f,0.f,0.f,0.f};
      char* xb = ((u + 1) & 1) ? xb1 : xb0;
      RUN_CHAIN(xb, wx_0, wx_1, axn0, axn1);
    }
    // D. h landed; B0 makes the shared tile visible block-wide
    asm volatile("s_waitcnt vmcnt(0)" ::: "memory");
    rawbar();
    __builtin_amdgcn_sched_barrier(0);
    // E. h-GEMM(u) + gate staging
    ah0 = (f32x4){0.f,0.f,0.f,0.f}; ah1 = (f32x4){0.f,0.f,0.f,0.f};
    RUN_CHAIN(smem + HB_OFF, wh_0, wh_1, ah0, ah1);
    write_gld(axc0 + ah0, axc1 + ah1);
    asm volatile("s_waitcnt lgkmcnt(0)" ::: "memory");
    rawbar();
    __builtin_amdgcn_sched_barrier(0);
    // G. elementwise + single h/seq store; then next-next x prefetch
    elem(u, hout);
    if (pf) {
      issue_x(u + 2, (u & 1) ? xb1 : xb0);
      // I. stores (older) drained; the 4 newest x-loads stay in flight
      asm volatile("s_waitcnt vmcnt(4)" ::: "memory");
      // J. publish early -- counter travels while we drain the prefetch
      publish();
      // I2. x(u+2) landed (overlaps peers' detect)
      asm volatile("s_waitcnt vmcnt(0)" ::: "memory");
    } else {
      asm volatile("s_waitcnt vmcnt(0)" ::: "memory");
      publish();
    }
    rawbar();   // B2: xb(u+2) ready block-wide; gld reusable
    axc0 = axn0; axc1 = axn1;
  }
}

// ---- LayerNorm + dense2(relu) + dense3; one block per batch row ----
__global__ __launch_bounds__(256) void final_k(
    const float* __restrict__ h2, const float* __restrict__ gamma, const float* __restrict__ beta,
    const float* __restrict__ W2, const float* __restrict__ b2,
    const float* __restrict__ W3, const float* __restrict__ b3, float* __restrict__ out)
{
  __shared__ float y[512];
  __shared__ float redS[4], redQ[4], redP[4];
  int b = blockIdx.x, tid = threadIdx.x;
  int wave = tid >> 6, lane = tid & 63;
  float v0 = h2[b * H_ + tid], v1 = h2[b * H_ + 256 + tid];
  float s = v0 + v1, q = v0 * v0 + v1 * v1;
#pragma unroll
  for (int o = 32; o; o >>= 1) { s += __shfl_down(s, o); q += __shfl_down(q, o); }
  if (lane == 0) { redS[wave] = s; redQ[wave] = q; }
  __syncthreads();
  float tot = redS[0] + redS[1] + redS[2] + redS[3];
  float totq = redQ[0] + redQ[1] + redQ[2] + redQ[3];
  float mu = tot * (1.f / 512.f);
  float var = totq * (1.f / 512.f) - mu * mu;
  float rs = rsqrtf(var + 1e-3f);
  y[tid]       = (v0 - mu) * rs * gamma[tid] + beta[tid];
  y[tid + 256] = (v1 - mu) * rs * gamma[tid + 256] + beta[tid + 256];
  __syncthreads();
  float acc = b2[tid];
  for (int k = 0; k < 512; k++) acc += y[k] * W2[k * 256 + tid];
  float pv = fmaxf(acc, 0.f) * W3[tid];
#pragma unroll
  for (int o = 32; o; o >>= 1) pv += __shfl_down(pv, o);
  if (lane == 0) redP[wave] = pv;
  __syncthreads();
  if (tid == 0) out[b] = redP[0] + redP[1] + redP[2] + redP[3] + b3[0];
}

extern "C" void kernel_launch(void* const* d_in, const int* in_sizes, int n_in,
                              void* d_out, int out_size, void* d_ws, size_t ws_size,
                              hipStream_t stream)
{
  (void)in_sizes; (void)n_in; (void)out_size; (void)ws_size;
  const float* x    = (const float*)d_in[0];
  const float* W1   = (const float*)d_in[1];
  const float* b1   = (const float*)d_in[2];
  const float* Wx1  = (const float*)d_in[3];
  const float* Wh1  = (const float*)d_in[4];
  const float* bl1  = (const float*)d_in[5];
  const float* Wx2  = (const float*)d_in[6];
  const float* Wh2  = (const float*)d_in[7];
  const float* bl2  = (const float*)d_in[8];
  const float* gam  = (const float*)d_in[9];
  const float* bet  = (const float*)d_in[10];
  const float* W2   = (const float*)d_in[11];
  const float* b2   = (const float*)d_in[12];
  const float* W3   = (const float*)d_in[13];
  const float* b3   = (const float*)d_in[14];

  char* p = (char*)d_ws;
  const size_t MB = 1024 * 1024;
  __hip_bfloat16* wx1t = (__hip_bfloat16*)(p + 0 * MB);
  __hip_bfloat16* wh1t = (__hip_bfloat16*)(p + 2 * MB);
  __hip_bfloat16* wx2t = (__hip_bfloat16*)(p + 4 * MB);
  __hip_bfloat16* wh2t = (__hip_bfloat16*)(p + 6 * MB);
  __hip_bfloat16* w1b  = (__hip_bfloat16*)(p + 8 * MB);
  __hip_bfloat16* h0   = (__hip_bfloat16*)(p + 9 * MB);   // 32 MB
  __hip_bfloat16* seq  = (__hip_bfloat16*)(p + 41 * MB);  // 32 MB
  char* st = p + 73 * MB;
  __hip_bfloat16* h1A = (__hip_bfloat16*)st;                       // 4x128KB
  __hip_bfloat16* h1B = h1A + B_ * H_;
  __hip_bfloat16* h2A = h1B + B_ * H_;
  __hip_bfloat16* h2B = h2A + B_ * H_;
  float* h2f = (float*)(st + 512 * 1024);                          // 256KB
  unsigned* flags = (unsigned*)(st + 512 * 1024 + 256 * 1024);     // 8KB counters
  int nzero = (int)((512 * 1024 + 256 * 1024 + 16384) / 4);

  transpose_cast_k<<<dim3(32, 8, 4), 256, 0, stream>>>(Wx1, Wh1, Wx2, Wh2, wx1t);
  prep_misc_k<<<256, 256, 0, stream>>>(W1, w1b, (float*)st, nzero);
  dense1_k<<<1024, 512, 0, stream>>>(x, w1b, b1, h0);

  void* args[] = { (void*)&h0, (void*)&seq,
                   (void*)&wh1t, (void*)&wx1t, (void*)&bl1,
                   (void*)&wh2t, (void*)&wx2t, (void*)&bl2,
                   (void*)&h1A, (void*)&h1B, (void*)&h2A, (void*)&h2B,
                   (void*)&h2f, (void*)&flags };
  hipLaunchCooperativeKernel((void*)lstm_fused_k, dim3(256), dim3(512), args,
                             SMEM_TOTAL, stream);

  final_k<<<128, 256, 0, stream>>>(h2f, gam, bet, W2, b2, W3, b3, (float*)d_out);
}